// Round 10
// baseline (675.282 us; speedup 1.0000x reference)
//
#include <hip/hip_runtime.h>

// Problem constants
#define NNODES 65536
#define NEDGES 524288
#define MSG_LDA 320  // msg LDS row stride (elems); 64*320*2 = 40960 B -> 4 blocks/CU

typedef short bf16x8 __attribute__((ext_vector_type(8)));
typedef float f32x4 __attribute__((ext_vector_type(4)));

// Packed-weight fragment offsets (in bf16 elements) within the weight region.
// Fragment layout per matrix (K x NC): [n_tile][k_tile][lane][8], 512 bf16 per fragment.
#define OF_MW1 0        // 320x256: KT=10, NT=16 -> 81920
#define OF_MW2 81920    // 256x256: KT=8,  NT=16 -> 65536
#define OF_MW3 147456   // 256x128: KT=8,  NT=8  -> 32768
#define OF_UW1 180224   // 384x256: KT=12, NT=16 -> 98304
#define OF_UW2 278528   // 256x256: KT=8,  NT=16 -> 65536
#define OF_UW3 344064   // 256x128: KT=8,  NT=8  -> 32768
#define WF_BYTES (376832 * 2)

// Big-workspace layout (CSR path)
#define WS_MSGS_BYTES ((size_t)NEDGES * 128 * 2)          // 134217728 (bf16)
#define WS_EIDX_OFF   WS_MSGS_BYTES
#define WS_EIDX_BYTES ((size_t)NNODES * 64 * 4)           // 16777216
#define WS_CNT_OFF    (WS_EIDX_OFF + WS_EIDX_BYTES)
#define WS_CNT_BYTES  ((size_t)NNODES * 4)                // 262144
#define WS_WF_OFF     (WS_CNT_OFF + WS_CNT_BYTES)
#define WS_NEED       (WS_WF_OFF + WF_BYTES)

// Fallback layout (atomic path)
#define WS_SUMMED_BYTES ((size_t)NNODES * 128 * 4)

__device__ __forceinline__ unsigned short f2bf(float x) {
  unsigned int u = __float_as_uint(x);
  return (unsigned short)((u + 0x7FFFu + ((u >> 16) & 1u)) >> 16);  // RNE
}

__device__ __forceinline__ float bf2f(short s) {
  return __uint_as_float((unsigned int)(unsigned short)s << 16);
}

// v_cvt_pk_bf16_f32 (RNE): result.lo16 = bf16(a), result.hi16 = bf16(b).
__device__ __forceinline__ unsigned int cvtpk(float a, float b) {
  unsigned int r;
  asm("v_cvt_pk_bf16_f32 %0, %1, %2" : "=v"(r) : "v"(a), "v"(b));
  return r;
}

// Pack 8 f32 -> 8 bf16 (one 16B store) via 4 packed converts.
__device__ __forceinline__ void cvt_store8(unsigned short* p, float4 a, float4 b) {
  *reinterpret_cast<uint4*>(p) =
      make_uint4(cvtpk(a.x, a.y), cvtpk(a.z, a.w), cvtpk(b.x, b.y), cvtpk(b.z, b.w));
}

// Swizzled Xs address for the msg kernel: row-stride 320 elems with byte XOR
// ((row&7)<<4). Stride 320 alone is bank-degenerate (160 dw = 0 mod 32); the XOR
// spreads 8 consecutive rows across 8 distinct 16B slots -> conflict-free b128.
// XOR value is multiple of 16 -> preserves 8B/16B alignment; bijective per row.
__device__ __forceinline__ unsigned short* xswz(unsigned short* Xs, int row, int col) {
  return reinterpret_cast<unsigned short*>(
      reinterpret_cast<char*>(Xs) + (((row * MSG_LDA + col) * 2) ^ ((row & 7) << 4)));
}
__device__ __forceinline__ const unsigned short* xswz(const unsigned short* Xs, int row,
                                                      int col) {
  return reinterpret_cast<const unsigned short*>(
      reinterpret_cast<const char*>(Xs) + (((row * MSG_LDA + col) * 2) ^ ((row & 7) << 4)));
}

// Tile GEMM: A from LDS (1-deep prefetch), W fragments from L2 (2-deep prefetch).
// OPERAND-SWAPPED: mfma(b, a, c) computes (X W)^T:
//   acc[m][n] reg q = D[edge row = m*16 + (lane&15)][out col = n*16 + (lane>>4)*4 + q]
template <int MT, int KT, int NTW, bool SWZ>
__device__ __forceinline__ void gemm_tile(const unsigned short* A, const int lda,
                                          const unsigned short* Wf,
                                          f32x4 (&acc)[MT][NTW], const int lane) {
  const int ar = lane & 15;
  const int ak = (lane >> 4) << 3;

  auto ldA = [&](int m, int kt) -> bf16x8 {
    if constexpr (SWZ)
      return *reinterpret_cast<const bf16x8*>(xswz(A, m * 16 + ar, kt * 32 + ak));
    else
      return *reinterpret_cast<const bf16x8*>(&A[(m * 16 + ar) * lda + kt * 32 + ak]);
  };
  auto ldB = [&](int n, int kt) -> bf16x8 {
    return *reinterpret_cast<const bf16x8*>(&Wf[(size_t)(n * KT + kt) * 512 + lane * 8]);
  };

  bf16x8 b0[NTW], b1[NTW], acur[MT];
#pragma unroll
  for (int n = 0; n < NTW; ++n) b0[n] = ldB(n, 0);
  if constexpr (KT > 1) {
#pragma unroll
    for (int n = 0; n < NTW; ++n) b1[n] = ldB(n, 1);
  }
#pragma unroll
  for (int m = 0; m < MT; ++m) acur[m] = ldA(m, 0);

#pragma unroll
  for (int kt = 0; kt < KT; ++kt) {
    bf16x8 bnxt[NTW], anxt[MT];
    if (kt + 2 < KT) {
#pragma unroll
      for (int n = 0; n < NTW; ++n) bnxt[n] = ldB(n, kt + 2);
    }
    if (kt + 1 < KT) {
#pragma unroll
      for (int m = 0; m < MT; ++m) anxt[m] = ldA(m, kt + 1);
    }
    bf16x8 (&bc)[NTW] = (kt & 1) ? b1 : b0;  // kt is a literal under full unroll
#pragma unroll
    for (int n = 0; n < NTW; ++n)
#pragma unroll
      for (int m = 0; m < MT; ++m)
        acc[m][n] = __builtin_amdgcn_mfma_f32_16x16x32_bf16(bc[n], acur[m], acc[m][n], 0, 0, 0);
    if (kt + 2 < KT) {
#pragma unroll
      for (int n = 0; n < NTW; ++n) bc[n] = bnxt[n];
    }
    if (kt + 1 < KT) {
#pragma unroll
      for (int m = 0; m < MT; ++m) acur[m] = anxt[m];
    }
  }
}

// Convert all six weight matrices into MFMA B-fragment order (bf16).
__global__ void prep_weights(const float* __restrict__ mW1, const float* __restrict__ mW2,
                             const float* __restrict__ mW3, const float* __restrict__ uW1,
                             const float* __restrict__ uW2, const float* __restrict__ uW3,
                             unsigned short* __restrict__ wf) {
  const int f = blockIdx.x;
  const int lane = threadIdx.x;
  const float* W; int NC, KT, fl, base;
  if (f < 160)      { W = mW1; NC = 256; KT = 10; fl = f;       base = OF_MW1; }
  else if (f < 288) { W = mW2; NC = 256; KT = 8;  fl = f - 160; base = OF_MW2; }
  else if (f < 352) { W = mW3; NC = 128; KT = 8;  fl = f - 288; base = OF_MW3; }
  else if (f < 544) { W = uW1; NC = 256; KT = 12; fl = f - 352; base = OF_UW1; }
  else if (f < 672) { W = uW2; NC = 256; KT = 8;  fl = f - 544; base = OF_UW2; }
  else              { W = uW3; NC = 128; KT = 8;  fl = f - 672; base = OF_UW3; }
  const int n_t = fl / KT;
  const int k_t = fl % KT;
  const int col = n_t * 16 + (lane & 15);
  const int krow = k_t * 32 + ((lane >> 4) << 3);
  unsigned short* dst = wf + base + (size_t)fl * 512 + lane * 8;
#pragma unroll
  for (int e = 0; e < 8; ++e) dst[e] = f2bf(W[(size_t)(krow + e) * NC + col]);
}

// Bucket fill: one thread per endpoint entry (2E total).
__global__ void fill_csr(const int* __restrict__ verts, int* __restrict__ cnt,
                         int* __restrict__ eidx) {
  const int k = blockIdx.x * 256 + threadIdx.x;
  const int v = verts[k];
  const int slot = atomicAdd(&cnt[v], 1);
  if (slot < 64) eidx[(size_t)v * 64 + slot] = k >> 1;  // message row = edge id
}

// Message MLP. 64 edges per workgroup, 4 waves, swizzled single LDS buffer
// [64][320] = 40960 B -> 4 blocks/CU. Merged staging (one barrier); swapped-MFMA
// vector epilogues; CSR path writes layer-3 straight from accumulators to global.
template <bool ATOMIC>
__global__ __launch_bounds__(256, 4) void msg_kernel(
    const float* __restrict__ ns, const float* __restrict__ edg,
    const int* __restrict__ verts, const unsigned short* __restrict__ wf,
    const float* __restrict__ mb1, const float* __restrict__ mb2,
    const float* __restrict__ mb3, float* __restrict__ summed,
    unsigned short* __restrict__ msgs) {
  extern __shared__ unsigned short smem[];
  unsigned short* Xs = smem;  // [64][320] swizzled; X cols 0..319, then H 0..255

  const int tid = threadIdx.x;
  const int lane = tid & 63;
  const int w = tid >> 6;
  const int e0 = blockIdx.x * 64;

  // Merged staging: [node_i | node_j | edge] -> Xs, ONE barrier.
  {
    const int r = tid >> 4;
    const int c = (tid & 15) * 8;
#pragma unroll
    for (int p = 0; p < 4; ++p) {
      const int row = p * 16 + r;
      const int2 vv = *reinterpret_cast<const int2*>(&verts[(size_t)(e0 + row) * 2]);
      const float4* s0 = reinterpret_cast<const float4*>(ns + (size_t)vv.x * 128 + c);
      cvt_store8(xswz(Xs, row, c), s0[0], s0[1]);
      const float4* s1 = reinterpret_cast<const float4*>(ns + (size_t)vv.y * 128 + c);
      cvt_store8(xswz(Xs, row, 128 + c), s1[0], s1[1]);
    }
#pragma unroll
    for (int i = tid; i < 512; i += 256) {
      const int row = i >> 3;
      const int cc = (i & 7) * 8;
      const float4* s2 = reinterpret_cast<const float4*>(edg + (size_t)(e0 + row) * 64 + cc);
      cvt_store8(xswz(Xs, row, 256 + cc), s2[0], s2[1]);
    }
  }
  __syncthreads();

  const int cw = lane & 15;          // edge row within m-tile (transposed layout)
  const int rq = (lane >> 4) * 4;    // first of this lane's 4 consecutive out-cols

  // Layer 1: 320 -> 256, relu. Each wave: 64 output cols. H written back into Xs.
  {
    f32x4 acc[4][4];
#pragma unroll
    for (int m = 0; m < 4; ++m)
#pragma unroll
      for (int n = 0; n < 4; ++n)
#pragma unroll
        for (int i = 0; i < 4; ++i) acc[m][n][i] = 0.0f;
    gemm_tile<4, 10, 4, true>(Xs, MSG_LDA, wf + OF_MW1 + (size_t)(w * 4) * 10 * 512, acc, lane);
    __syncthreads();
#pragma unroll
    for (int n = 0; n < 4; ++n) {
      const float4 bv = *reinterpret_cast<const float4*>(&mb1[w * 64 + n * 16 + rq]);
#pragma unroll
      for (int m = 0; m < 4; ++m) {
        const float x0 = fmaxf(acc[m][n][0] + bv.x, 0.0f);
        const float x1 = fmaxf(acc[m][n][1] + bv.y, 0.0f);
        const float x2 = fmaxf(acc[m][n][2] + bv.z, 0.0f);
        const float x3 = fmaxf(acc[m][n][3] + bv.w, 0.0f);
        *reinterpret_cast<uint2*>(xswz(Xs, m * 16 + cw, w * 64 + n * 16 + rq)) =
            make_uint2(cvtpk(x0, x1), cvtpk(x2, x3));
      }
    }
  }
  __syncthreads();

  // Layer 2: 256 -> 256, relu, in-place on Xs.
  {
    f32x4 acc[4][4];
#pragma unroll
    for (int m = 0; m < 4; ++m)
#pragma unroll
      for (int n = 0; n < 4; ++n)
#pragma unroll
        for (int i = 0; i < 4; ++i) acc[m][n][i] = 0.0f;
    gemm_tile<4, 8, 4, true>(Xs, MSG_LDA, wf + OF_MW2 + (size_t)(w * 4) * 8 * 512, acc, lane);
    __syncthreads();
#pragma unroll
    for (int n = 0; n < 4; ++n) {
      const float4 bv = *reinterpret_cast<const float4*>(&mb2[w * 64 + n * 16 + rq]);
#pragma unroll
      for (int m = 0; m < 4; ++m) {
        const float x0 = fmaxf(acc[m][n][0] + bv.x, 0.0f);
        const float x1 = fmaxf(acc[m][n][1] + bv.y, 0.0f);
        const float x2 = fmaxf(acc[m][n][2] + bv.z, 0.0f);
        const float x3 = fmaxf(acc[m][n][3] + bv.w, 0.0f);
        *reinterpret_cast<uint2*>(xswz(Xs, m * 16 + cw, w * 64 + n * 16 + rq)) =
            make_uint2(cvtpk(x0, x1), cvtpk(x2, x3));
      }
    }
  }
  __syncthreads();

  // Layer 3: 256 -> 128, straight from accumulators to output (no LDS, no barrier).
  {
    f32x4 acc[4][2];
#pragma unroll
    for (int m = 0; m < 4; ++m)
#pragma unroll
      for (int n = 0; n < 2; ++n)
#pragma unroll
        for (int i = 0; i < 4; ++i) acc[m][n][i] = 0.0f;
    gemm_tile<4, 8, 2, true>(Xs, MSG_LDA, wf + OF_MW3 + (size_t)(w * 2) * 8 * 512, acc, lane);

    if constexpr (ATOMIC) {
#pragma unroll
      for (int n = 0; n < 2; ++n) {
        const float4 bv = *reinterpret_cast<const float4*>(&mb3[w * 32 + n * 16 + rq]);
        const float* bp = &bv.x;
#pragma unroll
        for (int m = 0; m < 4; ++m) {
          const int row = m * 16 + cw;
          const int2 vv = *reinterpret_cast<const int2*>(&verts[(size_t)(e0 + row) * 2]);
#pragma unroll
          for (int q = 0; q < 4; ++q) {
            const int col = w * 32 + n * 16 + rq + q;
            const float v = acc[m][n][q] + bp[q];
            unsafeAtomicAdd(&summed[(size_t)vv.x * 128 + col], v);
            unsafeAtomicAdd(&summed[(size_t)vv.y * 128 + col], v);
          }
        }
      }
    } else {
#pragma unroll
      for (int n = 0; n < 2; ++n) {
        const float4 bv = *reinterpret_cast<const float4*>(&mb3[w * 32 + n * 16 + rq]);
#pragma unroll
        for (int m = 0; m < 4; ++m) {
          *reinterpret_cast<uint2*>(
              &msgs[(size_t)(e0 + m * 16 + cw) * 128 + w * 32 + n * 16 + rq]) =
              make_uint2(cvtpk(acc[m][n][0] + bv.x, acc[m][n][1] + bv.y),
                         cvtpk(acc[m][n][2] + bv.z, acc[m][n][3] + bv.w));
        }
      }
    }
  }
}

// Update MLP: 32 nodes per workgroup, 2 waves, NTW=8, single LDS buffer.
// LDS = 32*392*2 = 25088 B -> 6 blocks/CU (stride 392 = 98 dw = 2 mod 32: 2-way, free).
// attention[n] = ns[n] - ns[n^2048].
template <bool GATHER>
__global__ __launch_bounds__(128, 3) void upd_kernel(
    const float* __restrict__ ns, const float* __restrict__ summed,
    const unsigned short* __restrict__ msgs, const int* __restrict__ cnt,
    const int* __restrict__ eidx, const unsigned short* __restrict__ wf,
    const float* __restrict__ ub1, const float* __restrict__ ub2,
    const float* __restrict__ ub3, float* __restrict__ out) {
  extern __shared__ unsigned short smem[];
  unsigned short* Xs = smem;  // [32][392]; X cols 0..383, then H 0..255

  const int tid = threadIdx.x;
  const int lane = tid & 63;
  const int w = tid >> 6;
  const int n0 = blockIdx.x * 32;

  // Phase 1: node | attention -> Xs; summed read (fallback) or eidx staging (CSR).
  for (int i = tid; i < 512; i += 128) {
    const int row = i >> 4;
    const int c = (i & 15) * 8;
    const int n = n0 + row;
    const float4* sA = reinterpret_cast<const float4*>(ns + (size_t)n * 128 + c);
    const float4 a0 = sA[0], a1 = sA[1];
    cvt_store8(&Xs[row * 392 + c], a0, a1);
    if constexpr (!GATHER) {
      const float4* sS = reinterpret_cast<const float4*>(summed + (size_t)n * 128 + c);
      cvt_store8(&Xs[row * 392 + 128 + c], sS[0], sS[1]);
    }
    const float4* sP = reinterpret_cast<const float4*>(ns + (size_t)(n ^ 2048) * 128 + c);
    const float4 p0 = sP[0], p1 = sP[1];
    float4 d0, d1;
    d0.x = a0.x - p0.x; d0.y = a0.y - p0.y; d0.z = a0.z - p0.z; d0.w = a0.w - p0.w;
    d1.x = a1.x - p1.x; d1.y = a1.y - p1.y; d1.z = a1.z - p1.z; d1.w = a1.w - p1.w;
    cvt_store8(&Xs[row * 392 + 256 + c], d0, d1);
  }

  if constexpr (GATHER) {
    // Stage this tile's eidx lists into Xs cols 128..255 (64 ints per row).
    for (int i = tid; i < 512; i += 128) {
      const int row = i >> 4;
      const int q4 = i & 15;
      reinterpret_cast<int4*>(&Xs[row * 392 + 128])[q4] =
          reinterpret_cast<const int4*>(&eidx[(size_t)(n0 + row) * 64])[q4];
    }
    __syncthreads();

    // 4 threads per node, 32 cols each; fp32 accumulate in registers.
    const int nl = tid >> 2;
    const int part = tid & 3;
    const int cn = min(cnt[n0 + nl], 64);
    const int* el = reinterpret_cast<const int*>(&Xs[nl * 392 + 128]);
    float acc[32];
#pragma unroll
    for (int k = 0; k < 32; ++k) acc[k] = 0.0f;
    for (int j = 0; j < cn; ++j) {
      const int e = el[j];
      const bf16x8* mp = reinterpret_cast<const bf16x8*>(&msgs[(size_t)e * 128 + part * 32]);
#pragma unroll
      for (int t = 0; t < 4; ++t) {
        const bf16x8 v = mp[t];
#pragma unroll
        for (int k = 0; k < 8; ++k) acc[t * 8 + k] += bf2f(v[k]);
      }
    }
    __syncthreads();  // all eidx LDS reads done before overwrite
#pragma unroll
    for (int t = 0; t < 4; ++t) {
      *reinterpret_cast<uint4*>(&Xs[nl * 392 + 128 + part * 32 + t * 8]) =
          make_uint4(cvtpk(acc[t * 8 + 0], acc[t * 8 + 1]), cvtpk(acc[t * 8 + 2], acc[t * 8 + 3]),
                     cvtpk(acc[t * 8 + 4], acc[t * 8 + 5]), cvtpk(acc[t * 8 + 6], acc[t * 8 + 7]));
    }
  }
  __syncthreads();

  const int cw = lane & 15;
  const int rq = (lane >> 4) * 4;

  // Layer 1: 384 -> 256, relu. Each wave: 128 output cols. H back into Xs.
  {
    f32x4 acc[2][8];
#pragma unroll
    for (int m = 0; m < 2; ++m)
#pragma unroll
      for (int n = 0; n < 8; ++n)
#pragma unroll
        for (int i = 0; i < 4; ++i) acc[m][n][i] = 0.0f;
    gemm_tile<2, 12, 8, false>(Xs, 392, wf + OF_UW1 + (size_t)(w * 8) * 12 * 512, acc, lane);
    __syncthreads();
#pragma unroll
    for (int n = 0; n < 8; ++n) {
      const float4 bv = *reinterpret_cast<const float4*>(&ub1[w * 128 + n * 16 + rq]);
#pragma unroll
      for (int m = 0; m < 2; ++m) {
        const float x0 = fmaxf(acc[m][n][0] + bv.x, 0.0f);
        const float x1 = fmaxf(acc[m][n][1] + bv.y, 0.0f);
        const float x2 = fmaxf(acc[m][n][2] + bv.z, 0.0f);
        const float x3 = fmaxf(acc[m][n][3] + bv.w, 0.0f);
        *reinterpret_cast<uint2*>(&Xs[(m * 16 + cw) * 392 + w * 128 + n * 16 + rq]) =
            make_uint2(cvtpk(x0, x1), cvtpk(x2, x3));
      }
    }
  }
  __syncthreads();

  // Layer 2: 256 -> 256, relu, in-place on Xs.
  {
    f32x4 acc[2][8];
#pragma unroll
    for (int m = 0; m < 2; ++m)
#pragma unroll
      for (int n = 0; n < 8; ++n)
#pragma unroll
        for (int i = 0; i < 4; ++i) acc[m][n][i] = 0.0f;
    gemm_tile<2, 8, 8, false>(Xs, 392, wf + OF_UW2 + (size_t)(w * 8) * 8 * 512, acc, lane);
    __syncthreads();
#pragma unroll
    for (int n = 0; n < 8; ++n) {
      const float4 bv = *reinterpret_cast<const float4*>(&ub2[w * 128 + n * 16 + rq]);
#pragma unroll
      for (int m = 0; m < 2; ++m) {
        const float x0 = fmaxf(acc[m][n][0] + bv.x, 0.0f);
        const float x1 = fmaxf(acc[m][n][1] + bv.y, 0.0f);
        const float x2 = fmaxf(acc[m][n][2] + bv.z, 0.0f);
        const float x3 = fmaxf(acc[m][n][3] + bv.w, 0.0f);
        *reinterpret_cast<uint2*>(&Xs[(m * 16 + cw) * 392 + w * 128 + n * 16 + rq]) =
            make_uint2(cvtpk(x0, x1), cvtpk(x2, x3));
      }
    }
  }
  __syncthreads();

  // Layer 3: 256 -> 128 -> out (fp32 float4 stores). Each wave: 64 output cols.
  {
    f32x4 acc[2][4];
#pragma unroll
    for (int m = 0; m < 2; ++m)
#pragma unroll
      for (int n = 0; n < 4; ++n)
#pragma unroll
        for (int i = 0; i < 4; ++i) acc[m][n][i] = 0.0f;
    gemm_tile<2, 8, 4, false>(Xs, 392, wf + OF_UW3 + (size_t)(w * 4) * 8 * 512, acc, lane);
#pragma unroll
    for (int n = 0; n < 4; ++n) {
      const float4 bv = *reinterpret_cast<const float4*>(&ub3[w * 64 + n * 16 + rq]);
#pragma unroll
      for (int m = 0; m < 2; ++m) {
        const float4 o = make_float4(acc[m][n][0] + bv.x, acc[m][n][1] + bv.y,
                                     acc[m][n][2] + bv.z, acc[m][n][3] + bv.w);
        *reinterpret_cast<float4*>(
            &out[(size_t)(n0 + m * 16 + cw) * 128 + w * 64 + n * 16 + rq]) = o;
      }
    }
  }
}

extern "C" void kernel_launch(void* const* d_in, const int* in_sizes, int n_in,
                              void* d_out, int out_size, void* d_ws, size_t ws_size,
                              hipStream_t stream) {
  const float* ns   = (const float*)d_in[0];
  const float* edg  = (const float*)d_in[1];
  const int* verts  = (const int*)d_in[2];
  const float* mW1  = (const float*)d_in[3];
  const float* mb1  = (const float*)d_in[4];
  const float* mW2  = (const float*)d_in[5];
  const float* mb2  = (const float*)d_in[6];
  const float* mW3  = (const float*)d_in[7];
  const float* mb3  = (const float*)d_in[8];
  const float* uW1  = (const float*)d_in[9];
  const float* ub1  = (const float*)d_in[10];
  const float* uW2  = (const float*)d_in[11];
  const float* ub2  = (const float*)d_in[12];
  const float* uW3  = (const float*)d_in[13];
  const float* ub3  = (const float*)d_in[14];
  float* out = (float*)d_out;

  const int msg_lds = 64 * MSG_LDA * 2;  // 40960 B -> 4 blocks/CU
  const int upd_lds = 32 * 392 * 2;      // 25088 B -> 6 blocks/CU

  if (ws_size >= WS_NEED) {
    // CSR path: no fp32 scatter-atomics.
    unsigned short* msgs = (unsigned short*)d_ws;
    int* eidx = (int*)((char*)d_ws + WS_EIDX_OFF);
    int* cnt  = (int*)((char*)d_ws + WS_CNT_OFF);
    unsigned short* wf = (unsigned short*)((char*)d_ws + WS_WF_OFF);

    (void)hipMemsetAsync(cnt, 0, WS_CNT_BYTES, stream);
    prep_weights<<<736, 64, 0, stream>>>(mW1, mW2, mW3, uW1, uW2, uW3, wf);
    fill_csr<<<2 * NEDGES / 256, 256, 0, stream>>>(verts, cnt, eidx);
    msg_kernel<false><<<NEDGES / 64, 256, msg_lds, stream>>>(
        ns, edg, verts, wf, mb1, mb2, mb3, nullptr, msgs);
    upd_kernel<true><<<NNODES / 32, 128, upd_lds, stream>>>(
        ns, nullptr, msgs, cnt, eidx, wf, ub1, ub2, ub3, out);
  } else {
    // Fallback: atomic path.
    float* summed = (float*)d_ws;
    unsigned short* wf = (unsigned short*)((char*)d_ws + WS_SUMMED_BYTES);

    (void)hipMemsetAsync(summed, 0, WS_SUMMED_BYTES, stream);
    prep_weights<<<736, 64, 0, stream>>>(mW1, mW2, mW3, uW1, uW2, uW3, wf);
    msg_kernel<true><<<NEDGES / 64, 256, msg_lds, stream>>>(
        ns, edg, verts, wf, mb1, mb2, mb3, summed, nullptr);
    upd_kernel<false><<<NNODES / 32, 128, upd_lds, stream>>>(
        ns, summed, nullptr, nullptr, nullptr, wf, ub1, ub2, ub3, out);
  }
}

// Round 11
// 463.396 us; speedup vs baseline: 1.4572x; 1.4572x over previous
//
#include <hip/hip_runtime.h>

// Problem constants
#define NNODES 65536
#define NEDGES 524288

typedef short bf16x8 __attribute__((ext_vector_type(8)));
typedef float f32x4 __attribute__((ext_vector_type(4)));

// Packed-weight fragment offsets (in bf16 elements) within the weight region.
// Fragment layout per matrix (K x NC): [n_tile][k_tile][lane][8], 512 bf16 per fragment.
#define OF_MW1 0        // 320x256: KT=10, NT=16 -> 81920
#define OF_MW2 81920    // 256x256: KT=8,  NT=16 -> 65536
#define OF_MW3 147456   // 256x128: KT=8,  NT=8  -> 32768
#define OF_UW1 180224   // 384x256: KT=12, NT=16 -> 98304
#define OF_UW2 278528   // 256x256: KT=8,  NT=16 -> 65536
#define OF_UW3 344064   // 256x128: KT=8,  NT=8  -> 32768
#define WF_BYTES (376832 * 2)

// Big-workspace layout (CSR path)
#define WS_MSGS_BYTES ((size_t)NEDGES * 128 * 2)          // 134217728 (bf16)
#define WS_NSB_OFF    WS_MSGS_BYTES
#define WS_NSB_BYTES  ((size_t)NNODES * 128 * 2)          // 16777216 (bf16 node table)
#define WS_EIDX_OFF   (WS_NSB_OFF + WS_NSB_BYTES)
#define WS_EIDX_BYTES ((size_t)NNODES * 64 * 4)           // 16777216
#define WS_CNT_OFF    (WS_EIDX_OFF + WS_EIDX_BYTES)
#define WS_CNT_BYTES  ((size_t)NNODES * 4)                // 262144
#define WS_WF_OFF     (WS_CNT_OFF + WS_CNT_BYTES)
#define WS_NEED       (WS_WF_OFF + WF_BYTES)

// Fallback layout (atomic path)
#define WS_SUMMED_BYTES ((size_t)NNODES * 128 * 4)

__device__ __forceinline__ unsigned short f2bf(float x) {
  unsigned int u = __float_as_uint(x);
  return (unsigned short)((u + 0x7FFFu + ((u >> 16) & 1u)) >> 16);  // RNE
}

__device__ __forceinline__ float bf2f(short s) {
  return __uint_as_float((unsigned int)(unsigned short)s << 16);
}

// v_cvt_pk_bf16_f32 (RNE): result.lo16 = bf16(a), result.hi16 = bf16(b).
__device__ __forceinline__ unsigned int cvtpk(float a, float b) {
  unsigned int r;
  asm("v_cvt_pk_bf16_f32 %0, %1, %2" : "=v"(r) : "v"(a), "v"(b));
  return r;
}

// Pack 8 f32 -> 8 bf16 (one 16B store) via 4 packed converts.
__device__ __forceinline__ void cvt_store8(unsigned short* p, float4 a, float4 b) {
  *reinterpret_cast<uint4*>(p) =
      make_uint4(cvtpk(a.x, a.y), cvtpk(a.z, a.w), cvtpk(b.x, b.y), cvtpk(b.z, b.w));
}

// Tile GEMM from LDS with 1-deep register prefetch of next-kt A and B fragments.
template <int MT, int KT, int NTW>
__device__ __forceinline__ void gemm_tile(const unsigned short* A, const int lda,
                                          const unsigned short* Wf,
                                          f32x4 (&acc)[MT][NTW], const int lane) {
  const int ar = lane & 15;
  const int ak = (lane >> 4) << 3;
  bf16x8 bcur[NTW], acur[MT];
#pragma unroll
  for (int n = 0; n < NTW; ++n)
    bcur[n] = *reinterpret_cast<const bf16x8*>(&Wf[(size_t)(n * KT) * 512 + lane * 8]);
#pragma unroll
  for (int m = 0; m < MT; ++m)
    acur[m] = *reinterpret_cast<const bf16x8*>(&A[(m * 16 + ar) * lda + ak]);
#pragma unroll
  for (int kt = 0; kt < KT; ++kt) {
    bf16x8 bnxt[NTW], anxt[MT];
    if (kt + 1 < KT) {
#pragma unroll
      for (int n = 0; n < NTW; ++n)
        bnxt[n] = *reinterpret_cast<const bf16x8*>(
            &Wf[(size_t)(n * KT + kt + 1) * 512 + lane * 8]);
#pragma unroll
      for (int m = 0; m < MT; ++m)
        anxt[m] = *reinterpret_cast<const bf16x8*>(
            &A[(m * 16 + ar) * lda + (kt + 1) * 32 + ak]);
    }
#pragma unroll
    for (int n = 0; n < NTW; ++n)
#pragma unroll
      for (int m = 0; m < MT; ++m)
        acc[m][n] = __builtin_amdgcn_mfma_f32_16x16x32_bf16(acur[m], bcur[n], acc[m][n], 0, 0, 0);
    if (kt + 1 < KT) {
#pragma unroll
      for (int n = 0; n < NTW; ++n) bcur[n] = bnxt[n];
#pragma unroll
      for (int m = 0; m < MT; ++m) acur[m] = anxt[m];
    }
  }
}

// Convert all six weight matrices into MFMA B-fragment order (bf16).
__global__ void prep_weights(const float* __restrict__ mW1, const float* __restrict__ mW2,
                             const float* __restrict__ mW3, const float* __restrict__ uW1,
                             const float* __restrict__ uW2, const float* __restrict__ uW3,
                             unsigned short* __restrict__ wf) {
  const int f = blockIdx.x;
  const int lane = threadIdx.x;
  const float* W; int NC, KT, fl, base;
  if (f < 160)      { W = mW1; NC = 256; KT = 10; fl = f;       base = OF_MW1; }
  else if (f < 288) { W = mW2; NC = 256; KT = 8;  fl = f - 160; base = OF_MW2; }
  else if (f < 352) { W = mW3; NC = 128; KT = 8;  fl = f - 288; base = OF_MW3; }
  else if (f < 544) { W = uW1; NC = 256; KT = 12; fl = f - 352; base = OF_UW1; }
  else if (f < 672) { W = uW2; NC = 256; KT = 8;  fl = f - 544; base = OF_UW2; }
  else              { W = uW3; NC = 128; KT = 8;  fl = f - 672; base = OF_UW3; }
  const int n_t = fl / KT;
  const int k_t = fl % KT;
  const int col = n_t * 16 + (lane & 15);
  const int krow = k_t * 32 + ((lane >> 4) << 3);
  unsigned short* dst = wf + base + (size_t)fl * 512 + lane * 8;
#pragma unroll
  for (int e = 0; e < 8; ++e) dst[e] = f2bf(W[(size_t)(krow + e) * NC + col]);
}

// Stream-convert node_states to a bf16 table (same RNE as staging used before).
__global__ void cvt_ns(const float* __restrict__ ns, unsigned short* __restrict__ nsb) {
  const size_t i = ((size_t)blockIdx.x * 256 + threadIdx.x) * 8;
  const float4* s = reinterpret_cast<const float4*>(ns + i);
  cvt_store8(&nsb[i], s[0], s[1]);
}

// Bucket fill: one thread per endpoint entry (2E total).
__global__ void fill_csr(const int* __restrict__ verts, int* __restrict__ cnt,
                         int* __restrict__ eidx) {
  const int k = blockIdx.x * 256 + threadIdx.x;
  const int v = verts[k];
  const int slot = atomicAdd(&cnt[v], 1);
  if (slot < 64) eidx[(size_t)v * 64 + slot] = k >> 1;  // message row = edge id
}

// Message MLP. 64 edges per workgroup, 4 waves, single LDS buffer [64][328].
// CSR path gathers from the PRE-CONVERTED bf16 node table (half the gather bytes,
// zero cvt work); layer-3 writes straight from accumulators to global.
// LDS = 64*328*2 = 41984 B -> 3 blocks/CU.
template <bool ATOMIC>
__global__ __launch_bounds__(256, 3) void msg_kernel(
    const float* __restrict__ ns, const unsigned short* __restrict__ nsb,
    const float* __restrict__ edg, const int* __restrict__ verts,
    const unsigned short* __restrict__ wf, const float* __restrict__ mb1,
    const float* __restrict__ mb2, const float* __restrict__ mb3,
    float* __restrict__ summed, unsigned short* __restrict__ msgs) {
  extern __shared__ unsigned short smem[];
  unsigned short* Xs = smem;  // [64][328] bf16; X cols 0..319, then H 0..255

  const int tid = threadIdx.x;
  const int lane = tid & 63;
  const int w = tid >> 6;
  const int e0 = blockIdx.x * 64;

  // Merged staging: [node_i | node_j | edge] -> Xs, ONE barrier.
  {
    const int r = tid >> 4;
    const int c = (tid & 15) * 8;
#pragma unroll
    for (int p = 0; p < 4; ++p) {
      const int row = p * 16 + r;
      const int2 vv = *reinterpret_cast<const int2*>(&verts[(size_t)(e0 + row) * 2]);
      if constexpr (ATOMIC) {
        const float4* s0 = reinterpret_cast<const float4*>(ns + (size_t)vv.x * 128 + c);
        cvt_store8(&Xs[row * 328 + c], s0[0], s0[1]);
        const float4* s1 = reinterpret_cast<const float4*>(ns + (size_t)vv.y * 128 + c);
        cvt_store8(&Xs[row * 328 + 128 + c], s1[0], s1[1]);
      } else {
        *reinterpret_cast<bf16x8*>(&Xs[row * 328 + c]) =
            *reinterpret_cast<const bf16x8*>(&nsb[(size_t)vv.x * 128 + c]);
        *reinterpret_cast<bf16x8*>(&Xs[row * 328 + 128 + c]) =
            *reinterpret_cast<const bf16x8*>(&nsb[(size_t)vv.y * 128 + c]);
      }
    }
#pragma unroll
    for (int i = tid; i < 512; i += 256) {
      const int row = i >> 3;
      const int cc = (i & 7) * 8;
      const float4* s2 = reinterpret_cast<const float4*>(edg + (size_t)(e0 + row) * 64 + cc);
      cvt_store8(&Xs[row * 328 + 256 + cc], s2[0], s2[1]);
    }
  }
  __syncthreads();

  const int cw = lane & 15;
  const int rq = (lane >> 4) * 4;

  // Layer 1: 320 -> 256, relu. Each wave: 64 output cols. H written back into Xs.
  {
    f32x4 acc[4][4];
#pragma unroll
    for (int m = 0; m < 4; ++m)
#pragma unroll
      for (int n = 0; n < 4; ++n)
#pragma unroll
        for (int i = 0; i < 4; ++i) acc[m][n][i] = 0.0f;
    gemm_tile<4, 10, 4>(Xs, 328, wf + OF_MW1 + (size_t)(w * 4) * 10 * 512, acc, lane);
    __syncthreads();
#pragma unroll
    for (int n = 0; n < 4; ++n) {
      const int col = w * 64 + n * 16 + cw;
      const float bias = mb1[col];
#pragma unroll
      for (int m = 0; m < 4; ++m)
#pragma unroll
        for (int q = 0; q < 4; ++q) {
          const int row = m * 16 + rq + q;
          Xs[row * 328 + col] = f2bf(fmaxf(acc[m][n][q] + bias, 0.0f));
        }
    }
  }
  __syncthreads();

  // Layer 2: 256 -> 256, relu, in-place on Xs.
  {
    f32x4 acc[4][4];
#pragma unroll
    for (int m = 0; m < 4; ++m)
#pragma unroll
      for (int n = 0; n < 4; ++n)
#pragma unroll
        for (int i = 0; i < 4; ++i) acc[m][n][i] = 0.0f;
    gemm_tile<4, 8, 4>(Xs, 328, wf + OF_MW2 + (size_t)(w * 4) * 8 * 512, acc, lane);
    __syncthreads();
#pragma unroll
    for (int n = 0; n < 4; ++n) {
      const int col = w * 64 + n * 16 + cw;
      const float bias = mb2[col];
#pragma unroll
      for (int m = 0; m < 4; ++m)
#pragma unroll
        for (int q = 0; q < 4; ++q) {
          const int row = m * 16 + rq + q;
          Xs[row * 328 + col] = f2bf(fmaxf(acc[m][n][q] + bias, 0.0f));
        }
    }
  }
  __syncthreads();

  // Layer 3: 256 -> 128, straight from accumulators to output (no LDS, no barrier).
  {
    f32x4 acc[4][2];
#pragma unroll
    for (int m = 0; m < 4; ++m)
#pragma unroll
      for (int n = 0; n < 2; ++n)
#pragma unroll
        for (int i = 0; i < 4; ++i) acc[m][n][i] = 0.0f;
    gemm_tile<4, 8, 2>(Xs, 328, wf + OF_MW3 + (size_t)(w * 2) * 8 * 512, acc, lane);

    if constexpr (ATOMIC) {
#pragma unroll
      for (int n = 0; n < 2; ++n) {
        const int col = w * 32 + n * 16 + cw;
        const float bias = mb3[col];
#pragma unroll
        for (int m = 0; m < 4; ++m)
#pragma unroll
          for (int q = 0; q < 4; ++q) {
            const int row = m * 16 + rq + q;
            const int2 vv = *reinterpret_cast<const int2*>(&verts[(size_t)(e0 + row) * 2]);
            const float v = acc[m][n][q] + bias;
            unsafeAtomicAdd(&summed[(size_t)vv.x * 128 + col], v);
            unsafeAtomicAdd(&summed[(size_t)vv.y * 128 + col], v);
          }
      }
    } else {
#pragma unroll
      for (int n = 0; n < 2; ++n) {
        const int col = w * 32 + n * 16 + cw;
        const float bias = mb3[col];
#pragma unroll
        for (int m = 0; m < 4; ++m)
#pragma unroll
          for (int q = 0; q < 4; ++q) {
            const int row = m * 16 + rq + q;
            msgs[(size_t)(e0 + row) * 128 + col] = f2bf(acc[m][n][q] + bias);
          }
      }
    }
  }
}

// Update MLP: 32 nodes per workgroup, 2 waves, NTW=8, single LDS buffer.
// LDS = 32*392*2 = 25088 B -> 6 blocks/CU. attention[n] = ns[n] - ns[n^2048].
template <bool GATHER>
__global__ __launch_bounds__(128, 3) void upd_kernel(
    const float* __restrict__ ns, const float* __restrict__ summed,
    const unsigned short* __restrict__ msgs, const int* __restrict__ cnt,
    const int* __restrict__ eidx, const unsigned short* __restrict__ wf,
    const float* __restrict__ ub1, const float* __restrict__ ub2,
    const float* __restrict__ ub3, float* __restrict__ out) {
  extern __shared__ unsigned short smem[];
  unsigned short* Xs = smem;  // [32][392]; X cols 0..383, then H 0..255

  const int tid = threadIdx.x;
  const int lane = tid & 63;
  const int w = tid >> 6;
  const int n0 = blockIdx.x * 32;

  // Phase 1: node | attention -> Xs; summed read (fallback) or eidx staging (CSR).
  for (int i = tid; i < 512; i += 128) {
    const int row = i >> 4;
    const int c = (i & 15) * 8;
    const int n = n0 + row;
    const float4* sA = reinterpret_cast<const float4*>(ns + (size_t)n * 128 + c);
    const float4 a0 = sA[0], a1 = sA[1];
    cvt_store8(&Xs[row * 392 + c], a0, a1);
    if constexpr (!GATHER) {
      const float4* sS = reinterpret_cast<const float4*>(summed + (size_t)n * 128 + c);
      cvt_store8(&Xs[row * 392 + 128 + c], sS[0], sS[1]);
    }
    const float4* sP = reinterpret_cast<const float4*>(ns + (size_t)(n ^ 2048) * 128 + c);
    const float4 p0 = sP[0], p1 = sP[1];
    float4 d0, d1;
    d0.x = a0.x - p0.x; d0.y = a0.y - p0.y; d0.z = a0.z - p0.z; d0.w = a0.w - p0.w;
    d1.x = a1.x - p1.x; d1.y = a1.y - p1.y; d1.z = a1.z - p1.z; d1.w = a1.w - p1.w;
    cvt_store8(&Xs[row * 392 + 256 + c], d0, d1);
  }

  if constexpr (GATHER) {
    // Stage this tile's eidx lists into Xs cols 128..255 (64 ints per row).
    for (int i = tid; i < 512; i += 128) {
      const int row = i >> 4;
      const int q4 = i & 15;
      reinterpret_cast<int4*>(&Xs[row * 392 + 128])[q4] =
          reinterpret_cast<const int4*>(&eidx[(size_t)(n0 + row) * 64])[q4];
    }
    __syncthreads();

    // 4 threads per node, 32 cols each; fp32 accumulate in registers.
    const int nl = tid >> 2;
    const int part = tid & 3;
    const int cn = min(cnt[n0 + nl], 64);
    const int* el = reinterpret_cast<const int*>(&Xs[nl * 392 + 128]);
    float acc[32];
#pragma unroll
    for (int k = 0; k < 32; ++k) acc[k] = 0.0f;
    for (int j = 0; j < cn; ++j) {
      const int e = el[j];
      const bf16x8* mp = reinterpret_cast<const bf16x8*>(&msgs[(size_t)e * 128 + part * 32]);
#pragma unroll
      for (int t = 0; t < 4; ++t) {
        const bf16x8 v = mp[t];
#pragma unroll
        for (int k = 0; k < 8; ++k) acc[t * 8 + k] += bf2f(v[k]);
      }
    }
    __syncthreads();  // all eidx LDS reads done before overwrite
#pragma unroll
    for (int t = 0; t < 4; ++t) {
      *reinterpret_cast<uint4*>(&Xs[nl * 392 + 128 + part * 32 + t * 8]) =
          make_uint4(cvtpk(acc[t * 8 + 0], acc[t * 8 + 1]), cvtpk(acc[t * 8 + 2], acc[t * 8 + 3]),
                     cvtpk(acc[t * 8 + 4], acc[t * 8 + 5]), cvtpk(acc[t * 8 + 6], acc[t * 8 + 7]));
    }
  }
  __syncthreads();

  const int cw = lane & 15;
  const int rq = (lane >> 4) * 4;

  // Layer 1: 384 -> 256, relu. Each wave: 128 output cols. H back into Xs.
  {
    f32x4 acc[2][8];
#pragma unroll
    for (int m = 0; m < 2; ++m)
#pragma unroll
      for (int n = 0; n < 8; ++n)
#pragma unroll
        for (int i = 0; i < 4; ++i) acc[m][n][i] = 0.0f;
    gemm_tile<2, 12, 8>(Xs, 392, wf + OF_UW1 + (size_t)(w * 8) * 12 * 512, acc, lane);
    __syncthreads();
#pragma unroll
    for (int n = 0; n < 8; ++n) {
      const int col = w * 128 + n * 16 + cw;
      const float bias = ub1[col];
#pragma unroll
      for (int m = 0; m < 2; ++m)
#pragma unroll
        for (int q = 0; q < 4; ++q) {
          const int row = m * 16 + rq + q;
          Xs[row * 392 + col] = f2bf(fmaxf(acc[m][n][q] + bias, 0.0f));
        }
    }
  }
  __syncthreads();

  // Layer 2: 256 -> 256, relu, in-place on Xs.
  {
    f32x4 acc[2][8];
#pragma unroll
    for (int m = 0; m < 2; ++m)
#pragma unroll
      for (int n = 0; n < 8; ++n)
#pragma unroll
        for (int i = 0; i < 4; ++i) acc[m][n][i] = 0.0f;
    gemm_tile<2, 8, 8>(Xs, 392, wf + OF_UW2 + (size_t)(w * 8) * 8 * 512, acc, lane);
    __syncthreads();
#pragma unroll
    for (int n = 0; n < 8; ++n) {
      const int col = w * 128 + n * 16 + cw;
      const float bias = ub2[col];
#pragma unroll
      for (int m = 0; m < 2; ++m)
#pragma unroll
        for (int q = 0; q < 4; ++q) {
          const int row = m * 16 + rq + q;
          Xs[row * 392 + col] = f2bf(fmaxf(acc[m][n][q] + bias, 0.0f));
        }
    }
  }
  __syncthreads();

  // Layer 3: 256 -> 128 -> out (fp32). Each wave: 64 output cols.
  {
    f32x4 acc[2][4];
#pragma unroll
    for (int m = 0; m < 2; ++m)
#pragma unroll
      for (int n = 0; n < 4; ++n)
#pragma unroll
        for (int i = 0; i < 4; ++i) acc[m][n][i] = 0.0f;
    gemm_tile<2, 8, 4>(Xs, 392, wf + OF_UW3 + (size_t)(w * 4) * 8 * 512, acc, lane);
#pragma unroll
    for (int n = 0; n < 4; ++n) {
      const int col = w * 64 + n * 16 + cw;
      const float bias = ub3[col];
#pragma unroll
      for (int m = 0; m < 2; ++m)
#pragma unroll
        for (int q = 0; q < 4; ++q) {
          const int row = m * 16 + rq + q;
          out[(size_t)(n0 + row) * 128 + col] = acc[m][n][q] + bias;
        }
    }
  }
}

extern "C" void kernel_launch(void* const* d_in, const int* in_sizes, int n_in,
                              void* d_out, int out_size, void* d_ws, size_t ws_size,
                              hipStream_t stream) {
  const float* ns   = (const float*)d_in[0];
  const float* edg  = (const float*)d_in[1];
  const int* verts  = (const int*)d_in[2];
  const float* mW1  = (const float*)d_in[3];
  const float* mb1  = (const float*)d_in[4];
  const float* mW2  = (const float*)d_in[5];
  const float* mb2  = (const float*)d_in[6];
  const float* mW3  = (const float*)d_in[7];
  const float* mb3  = (const float*)d_in[8];
  const float* uW1  = (const float*)d_in[9];
  const float* ub1  = (const float*)d_in[10];
  const float* uW2  = (const float*)d_in[11];
  const float* ub2  = (const float*)d_in[12];
  const float* uW3  = (const float*)d_in[13];
  const float* ub3  = (const float*)d_in[14];
  float* out = (float*)d_out;

  const int msg_lds = 64 * 328 * 2;  // 41984 B -> 3 blocks/CU
  const int upd_lds = 32 * 392 * 2;  // 25088 B -> 6 blocks/CU

  if (ws_size >= WS_NEED) {
    // CSR path: no fp32 scatter-atomics; bf16 node table for the gather.
    unsigned short* msgs = (unsigned short*)d_ws;
    unsigned short* nsb  = (unsigned short*)((char*)d_ws + WS_NSB_OFF);
    int* eidx = (int*)((char*)d_ws + WS_EIDX_OFF);
    int* cnt  = (int*)((char*)d_ws + WS_CNT_OFF);
    unsigned short* wf = (unsigned short*)((char*)d_ws + WS_WF_OFF);

    (void)hipMemsetAsync(cnt, 0, WS_CNT_BYTES, stream);
    prep_weights<<<736, 64, 0, stream>>>(mW1, mW2, mW3, uW1, uW2, uW3, wf);
    cvt_ns<<<NNODES * 128 / 8 / 256, 256, 0, stream>>>(ns, nsb);
    fill_csr<<<2 * NEDGES / 256, 256, 0, stream>>>(verts, cnt, eidx);
    msg_kernel<false><<<NEDGES / 64, 256, msg_lds, stream>>>(
        ns, nsb, edg, verts, wf, mb1, mb2, mb3, nullptr, msgs);
    upd_kernel<true><<<NNODES / 32, 128, upd_lds, stream>>>(
        ns, nullptr, msgs, cnt, eidx, wf, ub1, ub2, ub3, out);
  } else {
    // Fallback: atomic path.
    float* summed = (float*)d_ws;
    unsigned short* wf = (unsigned short*)((char*)d_ws + WS_SUMMED_BYTES);

    (void)hipMemsetAsync(summed, 0, WS_SUMMED_BYTES, stream);
    prep_weights<<<736, 64, 0, stream>>>(mW1, mW2, mW3, uW1, uW2, uW3, wf);
    msg_kernel<true><<<NEDGES / 64, 256, msg_lds, stream>>>(
        ns, nullptr, edg, verts, wf, mb1, mb2, mb3, summed, nullptr);
    upd_kernel<false><<<NNODES / 32, 128, upd_lds, stream>>>(
        ns, summed, nullptr, nullptr, nullptr, wf, ub1, ub2, ub3, out);
  }
}

// Round 12
// 460.367 us; speedup vs baseline: 1.4668x; 1.0066x over previous
//
#include <hip/hip_runtime.h>

// Problem constants
#define NNODES 65536
#define NEDGES 524288

typedef short bf16x8 __attribute__((ext_vector_type(8)));
typedef float f32x4 __attribute__((ext_vector_type(4)));

// Packed-weight fragment offsets (in bf16 elements) within the weight region.
// Fragment layout per matrix (K x NC): [n_tile][k_tile][lane][8], 512 bf16 per fragment.
#define OF_MW1 0        // 320x256: KT=10, NT=16 -> 81920
#define OF_MW2 81920    // 256x256: KT=8,  NT=16 -> 65536
#define OF_MW3 147456   // 256x128: KT=8,  NT=8  -> 32768
#define OF_UW1 180224   // 384x256: KT=12, NT=16 -> 98304
#define OF_UW2 278528   // 256x256: KT=8,  NT=16 -> 65536
#define OF_UW3 344064   // 256x128: KT=8,  NT=8  -> 32768
#define WF_BYTES (376832 * 2)

// Big-workspace layout (CSR path)
#define WS_MSGS_BYTES ((size_t)NEDGES * 128 * 2)          // 134217728 (bf16)
#define WS_NSB_OFF    WS_MSGS_BYTES
#define WS_NSB_BYTES  ((size_t)NNODES * 128 * 2)          // 16777216 (bf16 node table)
#define WS_EIDX_OFF   (WS_NSB_OFF + WS_NSB_BYTES)
#define WS_EIDX_BYTES ((size_t)NNODES * 64 * 4)           // 16777216
#define WS_CNT_OFF    (WS_EIDX_OFF + WS_EIDX_BYTES)
#define WS_CNT_BYTES  ((size_t)NNODES * 4)                // 262144
#define WS_WF_OFF     (WS_CNT_OFF + WS_CNT_BYTES)
#define WS_NEED       (WS_WF_OFF + WF_BYTES)

// Fallback layout (atomic path)
#define WS_SUMMED_BYTES ((size_t)NNODES * 128 * 4)

__device__ __forceinline__ unsigned short f2bf(float x) {
  unsigned int u = __float_as_uint(x);
  return (unsigned short)((u + 0x7FFFu + ((u >> 16) & 1u)) >> 16);  // RNE
}

__device__ __forceinline__ float bf2f(short s) {
  return __uint_as_float((unsigned int)(unsigned short)s << 16);
}

// v_cvt_pk_bf16_f32 (RNE): result.lo16 = bf16(a), result.hi16 = bf16(b).
__device__ __forceinline__ unsigned int cvtpk(float a, float b) {
  unsigned int r;
  asm("v_cvt_pk_bf16_f32 %0, %1, %2" : "=v"(r) : "v"(a), "v"(b));
  return r;
}

// Pack 8 f32 -> 8 bf16 (one 16B store) via 4 packed converts.
__device__ __forceinline__ void cvt_store8(unsigned short* p, float4 a, float4 b) {
  *reinterpret_cast<uint4*>(p) =
      make_uint4(cvtpk(a.x, a.y), cvtpk(a.z, a.w), cvtpk(b.x, b.y), cvtpk(b.z, b.w));
}

// Tile GEMM, 1-deep prefetch (upd kernel; register-budget-friendly).
template <int MT, int KT, int NTW>
__device__ __forceinline__ void gemm_tile(const unsigned short* A, const int lda,
                                          const unsigned short* Wf,
                                          f32x4 (&acc)[MT][NTW], const int lane) {
  const int ar = lane & 15;
  const int ak = (lane >> 4) << 3;
  bf16x8 bcur[NTW], acur[MT];
#pragma unroll
  for (int n = 0; n < NTW; ++n)
    bcur[n] = *reinterpret_cast<const bf16x8*>(&Wf[(size_t)(n * KT) * 512 + lane * 8]);
#pragma unroll
  for (int m = 0; m < MT; ++m)
    acur[m] = *reinterpret_cast<const bf16x8*>(&A[(m * 16 + ar) * lda + ak]);
#pragma unroll
  for (int kt = 0; kt < KT; ++kt) {
    bf16x8 bnxt[NTW], anxt[MT];
    if (kt + 1 < KT) {
#pragma unroll
      for (int n = 0; n < NTW; ++n)
        bnxt[n] = *reinterpret_cast<const bf16x8*>(
            &Wf[(size_t)(n * KT + kt + 1) * 512 + lane * 8]);
#pragma unroll
      for (int m = 0; m < MT; ++m)
        anxt[m] = *reinterpret_cast<const bf16x8*>(
            &A[(m * 16 + ar) * lda + (kt + 1) * 32 + ak]);
    }
#pragma unroll
    for (int n = 0; n < NTW; ++n)
#pragma unroll
      for (int m = 0; m < MT; ++m)
        acc[m][n] = __builtin_amdgcn_mfma_f32_16x16x32_bf16(acur[m], bcur[n], acc[m][n], 0, 0, 0);
    if (kt + 1 < KT) {
#pragma unroll
      for (int n = 0; n < NTW; ++n) bcur[n] = bnxt[n];
#pragma unroll
      for (int m = 0; m < MT; ++m) acur[m] = anxt[m];
    }
  }
}

// Tile GEMM, 2-DEEP B prefetch (msg kernel): 3 rotating B buffers so two L2
// weight-fragment loads are in flight while kt's MFMAs issue. All buffer
// indices are compile-time constants under the full unroll (rule: no runtime
// indexing into register arrays).
template <int MT, int KT, int NTW>
__device__ __forceinline__ void gemm_tile_d2(const unsigned short* A, const int lda,
                                             const unsigned short* Wf,
                                             f32x4 (&acc)[MT][NTW], const int lane) {
  const int ar = lane & 15;
  const int ak = (lane >> 4) << 3;
  bf16x8 b[3][NTW];
  bf16x8 a2[2][MT];
#pragma unroll
  for (int n = 0; n < NTW; ++n)
    b[0][n] = *reinterpret_cast<const bf16x8*>(&Wf[(size_t)(n * KT) * 512 + lane * 8]);
  if constexpr (KT > 1) {
#pragma unroll
    for (int n = 0; n < NTW; ++n)
      b[1][n] = *reinterpret_cast<const bf16x8*>(&Wf[(size_t)(n * KT + 1) * 512 + lane * 8]);
  }
#pragma unroll
  for (int m = 0; m < MT; ++m)
    a2[0][m] = *reinterpret_cast<const bf16x8*>(&A[(m * 16 + ar) * lda + ak]);
#pragma unroll
  for (int kt = 0; kt < KT; ++kt) {
    if (kt + 2 < KT) {
#pragma unroll
      for (int n = 0; n < NTW; ++n)
        b[(kt + 2) % 3][n] = *reinterpret_cast<const bf16x8*>(
            &Wf[(size_t)(n * KT + kt + 2) * 512 + lane * 8]);
    }
    if (kt + 1 < KT) {
#pragma unroll
      for (int m = 0; m < MT; ++m)
        a2[(kt + 1) & 1][m] = *reinterpret_cast<const bf16x8*>(
            &A[(m * 16 + ar) * lda + (kt + 1) * 32 + ak]);
    }
#pragma unroll
    for (int n = 0; n < NTW; ++n)
#pragma unroll
      for (int m = 0; m < MT; ++m)
        acc[m][n] = __builtin_amdgcn_mfma_f32_16x16x32_bf16(a2[kt & 1][m], b[kt % 3][n],
                                                            acc[m][n], 0, 0, 0);
  }
}

// Convert all six weight matrices into MFMA B-fragment order (bf16).
__global__ void prep_weights(const float* __restrict__ mW1, const float* __restrict__ mW2,
                             const float* __restrict__ mW3, const float* __restrict__ uW1,
                             const float* __restrict__ uW2, const float* __restrict__ uW3,
                             unsigned short* __restrict__ wf) {
  const int f = blockIdx.x;
  const int lane = threadIdx.x;
  const float* W; int NC, KT, fl, base;
  if (f < 160)      { W = mW1; NC = 256; KT = 10; fl = f;       base = OF_MW1; }
  else if (f < 288) { W = mW2; NC = 256; KT = 8;  fl = f - 160; base = OF_MW2; }
  else if (f < 352) { W = mW3; NC = 128; KT = 8;  fl = f - 288; base = OF_MW3; }
  else if (f < 544) { W = uW1; NC = 256; KT = 12; fl = f - 352; base = OF_UW1; }
  else if (f < 672) { W = uW2; NC = 256; KT = 8;  fl = f - 544; base = OF_UW2; }
  else              { W = uW3; NC = 128; KT = 8;  fl = f - 672; base = OF_UW3; }
  const int n_t = fl / KT;
  const int k_t = fl % KT;
  const int col = n_t * 16 + (lane & 15);
  const int krow = k_t * 32 + ((lane >> 4) << 3);
  unsigned short* dst = wf + base + (size_t)fl * 512 + lane * 8;
#pragma unroll
  for (int e = 0; e < 8; ++e) dst[e] = f2bf(W[(size_t)(krow + e) * NC + col]);
}

// Stream-convert node_states to a bf16 table (same RNE as staging used before).
__global__ void cvt_ns(const float* __restrict__ ns, unsigned short* __restrict__ nsb) {
  const size_t i = ((size_t)blockIdx.x * 256 + threadIdx.x) * 8;
  const float4* s = reinterpret_cast<const float4*>(ns + i);
  cvt_store8(&nsb[i], s[0], s[1]);
}

// Bucket fill: one thread per endpoint entry (2E total).
__global__ void fill_csr(const int* __restrict__ verts, int* __restrict__ cnt,
                         int* __restrict__ eidx) {
  const int k = blockIdx.x * 256 + threadIdx.x;
  const int v = verts[k];
  const int slot = atomicAdd(&cnt[v], 1);
  if (slot < 64) eidx[(size_t)v * 64 + slot] = k >> 1;  // message row = edge id
}

// Message MLP. 64 edges per workgroup, 4 waves, single LDS buffer [64][328].
// CSR path gathers from the pre-converted bf16 node table; 2-deep B prefetch.
// LDS = 64*328*2 = 41984 B -> 3 blocks/CU.
template <bool ATOMIC>
__global__ __launch_bounds__(256, 3) void msg_kernel(
    const float* __restrict__ ns, const unsigned short* __restrict__ nsb,
    const float* __restrict__ edg, const int* __restrict__ verts,
    const unsigned short* __restrict__ wf, const float* __restrict__ mb1,
    const float* __restrict__ mb2, const float* __restrict__ mb3,
    float* __restrict__ summed, unsigned short* __restrict__ msgs) {
  extern __shared__ unsigned short smem[];
  unsigned short* Xs = smem;  // [64][328] bf16; X cols 0..319, then H 0..255

  const int tid = threadIdx.x;
  const int lane = tid & 63;
  const int w = tid >> 6;
  const int e0 = blockIdx.x * 64;

  // Merged staging: [node_i | node_j | edge] -> Xs, ONE barrier.
  {
    const int r = tid >> 4;
    const int c = (tid & 15) * 8;
#pragma unroll
    for (int p = 0; p < 4; ++p) {
      const int row = p * 16 + r;
      const int2 vv = *reinterpret_cast<const int2*>(&verts[(size_t)(e0 + row) * 2]);
      if constexpr (ATOMIC) {
        const float4* s0 = reinterpret_cast<const float4*>(ns + (size_t)vv.x * 128 + c);
        cvt_store8(&Xs[row * 328 + c], s0[0], s0[1]);
        const float4* s1 = reinterpret_cast<const float4*>(ns + (size_t)vv.y * 128 + c);
        cvt_store8(&Xs[row * 328 + 128 + c], s1[0], s1[1]);
      } else {
        *reinterpret_cast<bf16x8*>(&Xs[row * 328 + c]) =
            *reinterpret_cast<const bf16x8*>(&nsb[(size_t)vv.x * 128 + c]);
        *reinterpret_cast<bf16x8*>(&Xs[row * 328 + 128 + c]) =
            *reinterpret_cast<const bf16x8*>(&nsb[(size_t)vv.y * 128 + c]);
      }
    }
#pragma unroll
    for (int i = tid; i < 512; i += 256) {
      const int row = i >> 3;
      const int cc = (i & 7) * 8;
      const float4* s2 = reinterpret_cast<const float4*>(edg + (size_t)(e0 + row) * 64 + cc);
      cvt_store8(&Xs[row * 328 + 256 + cc], s2[0], s2[1]);
    }
  }
  __syncthreads();

  const int cw = lane & 15;
  const int rq = (lane >> 4) * 4;

  // Layer 1: 320 -> 256, relu. Each wave: 64 output cols. H written back into Xs.
  {
    f32x4 acc[4][4];
#pragma unroll
    for (int m = 0; m < 4; ++m)
#pragma unroll
      for (int n = 0; n < 4; ++n)
#pragma unroll
        for (int i = 0; i < 4; ++i) acc[m][n][i] = 0.0f;
    gemm_tile_d2<4, 10, 4>(Xs, 328, wf + OF_MW1 + (size_t)(w * 4) * 10 * 512, acc, lane);
    __syncthreads();
#pragma unroll
    for (int n = 0; n < 4; ++n) {
      const int col = w * 64 + n * 16 + cw;
      const float bias = mb1[col];
#pragma unroll
      for (int m = 0; m < 4; ++m)
#pragma unroll
        for (int q = 0; q < 4; ++q) {
          const int row = m * 16 + rq + q;
          Xs[row * 328 + col] = f2bf(fmaxf(acc[m][n][q] + bias, 0.0f));
        }
    }
  }
  __syncthreads();

  // Layer 2: 256 -> 256, relu, in-place on Xs.
  {
    f32x4 acc[4][4];
#pragma unroll
    for (int m = 0; m < 4; ++m)
#pragma unroll
      for (int n = 0; n < 4; ++n)
#pragma unroll
        for (int i = 0; i < 4; ++i) acc[m][n][i] = 0.0f;
    gemm_tile_d2<4, 8, 4>(Xs, 328, wf + OF_MW2 + (size_t)(w * 4) * 8 * 512, acc, lane);
    __syncthreads();
#pragma unroll
    for (int n = 0; n < 4; ++n) {
      const int col = w * 64 + n * 16 + cw;
      const float bias = mb2[col];
#pragma unroll
      for (int m = 0; m < 4; ++m)
#pragma unroll
        for (int q = 0; q < 4; ++q) {
          const int row = m * 16 + rq + q;
          Xs[row * 328 + col] = f2bf(fmaxf(acc[m][n][q] + bias, 0.0f));
        }
    }
  }
  __syncthreads();

  // Layer 3: 256 -> 128, straight from accumulators to output (no LDS, no barrier).
  {
    f32x4 acc[4][2];
#pragma unroll
    for (int m = 0; m < 4; ++m)
#pragma unroll
      for (int n = 0; n < 2; ++n)
#pragma unroll
        for (int i = 0; i < 4; ++i) acc[m][n][i] = 0.0f;
    gemm_tile_d2<4, 8, 2>(Xs, 328, wf + OF_MW3 + (size_t)(w * 2) * 8 * 512, acc, lane);

    if constexpr (ATOMIC) {
#pragma unroll
      for (int n = 0; n < 2; ++n) {
        const int col = w * 32 + n * 16 + cw;
        const float bias = mb3[col];
#pragma unroll
        for (int m = 0; m < 4; ++m)
#pragma unroll
          for (int q = 0; q < 4; ++q) {
            const int row = m * 16 + rq + q;
            const int2 vv = *reinterpret_cast<const int2*>(&verts[(size_t)(e0 + row) * 2]);
            const float v = acc[m][n][q] + bias;
            unsafeAtomicAdd(&summed[(size_t)vv.x * 128 + col], v);
            unsafeAtomicAdd(&summed[(size_t)vv.y * 128 + col], v);
          }
      }
    } else {
#pragma unroll
      for (int n = 0; n < 2; ++n) {
        const int col = w * 32 + n * 16 + cw;
        const float bias = mb3[col];
#pragma unroll
        for (int m = 0; m < 4; ++m)
#pragma unroll
          for (int q = 0; q < 4; ++q) {
            const int row = m * 16 + rq + q;
            msgs[(size_t)(e0 + row) * 128 + col] = f2bf(acc[m][n][q] + bias);
          }
      }
    }
  }
}

// Update MLP: 32 nodes per workgroup, 2 waves, NTW=8, single LDS buffer.
// LDS = 32*392*2 = 25088 B -> 6 blocks/CU. attention[n] = ns[n] - ns[n^2048].
template <bool GATHER>
__global__ __launch_bounds__(128, 3) void upd_kernel(
    const float* __restrict__ ns, const float* __restrict__ summed,
    const unsigned short* __restrict__ msgs, const int* __restrict__ cnt,
    const int* __restrict__ eidx, const unsigned short* __restrict__ wf,
    const float* __restrict__ ub1, const float* __restrict__ ub2,
    const float* __restrict__ ub3, float* __restrict__ out) {
  extern __shared__ unsigned short smem[];
  unsigned short* Xs = smem;  // [32][392]; X cols 0..383, then H 0..255

  const int tid = threadIdx.x;
  const int lane = tid & 63;
  const int w = tid >> 6;
  const int n0 = blockIdx.x * 32;

  // Phase 1: node | attention -> Xs; summed read (fallback) or eidx staging (CSR).
  for (int i = tid; i < 512; i += 128) {
    const int row = i >> 4;
    const int c = (i & 15) * 8;
    const int n = n0 + row;
    const float4* sA = reinterpret_cast<const float4*>(ns + (size_t)n * 128 + c);
    const float4 a0 = sA[0], a1 = sA[1];
    cvt_store8(&Xs[row * 392 + c], a0, a1);
    if constexpr (!GATHER) {
      const float4* sS = reinterpret_cast<const float4*>(summed + (size_t)n * 128 + c);
      cvt_store8(&Xs[row * 392 + 128 + c], sS[0], sS[1]);
    }
    const float4* sP = reinterpret_cast<const float4*>(ns + (size_t)(n ^ 2048) * 128 + c);
    const float4 p0 = sP[0], p1 = sP[1];
    float4 d0, d1;
    d0.x = a0.x - p0.x; d0.y = a0.y - p0.y; d0.z = a0.z - p0.z; d0.w = a0.w - p0.w;
    d1.x = a1.x - p1.x; d1.y = a1.y - p1.y; d1.z = a1.z - p1.z; d1.w = a1.w - p1.w;
    cvt_store8(&Xs[row * 392 + 256 + c], d0, d1);
  }

  if constexpr (GATHER) {
    // Stage this tile's eidx lists into Xs cols 128..255 (64 ints per row).
    for (int i = tid; i < 512; i += 128) {
      const int row = i >> 4;
      const int q4 = i & 15;
      reinterpret_cast<int4*>(&Xs[row * 392 + 128])[q4] =
          reinterpret_cast<const int4*>(&eidx[(size_t)(n0 + row) * 64])[q4];
    }
    __syncthreads();

    // 4 threads per node, 32 cols each; fp32 accumulate in registers.
    const int nl = tid >> 2;
    const int part = tid & 3;
    const int cn = min(cnt[n0 + nl], 64);
    const int* el = reinterpret_cast<const int*>(&Xs[nl * 392 + 128]);
    float acc[32];
#pragma unroll
    for (int k = 0; k < 32; ++k) acc[k] = 0.0f;
    for (int j = 0; j < cn; ++j) {
      const int e = el[j];
      const bf16x8* mp = reinterpret_cast<const bf16x8*>(&msgs[(size_t)e * 128 + part * 32]);
#pragma unroll
      for (int t = 0; t < 4; ++t) {
        const bf16x8 v = mp[t];
#pragma unroll
        for (int k = 0; k < 8; ++k) acc[t * 8 + k] += bf2f(v[k]);
      }
    }
    __syncthreads();  // all eidx LDS reads done before overwrite
#pragma unroll
    for (int t = 0; t < 4; ++t) {
      *reinterpret_cast<uint4*>(&Xs[nl * 392 + 128 + part * 32 + t * 8]) =
          make_uint4(cvtpk(acc[t * 8 + 0], acc[t * 8 + 1]), cvtpk(acc[t * 8 + 2], acc[t * 8 + 3]),
                     cvtpk(acc[t * 8 + 4], acc[t * 8 + 5]), cvtpk(acc[t * 8 + 6], acc[t * 8 + 7]));
    }
  }
  __syncthreads();

  const int cw = lane & 15;
  const int rq = (lane >> 4) * 4;

  // Layer 1: 384 -> 256, relu. Each wave: 128 output cols. H back into Xs.
  {
    f32x4 acc[2][8];
#pragma unroll
    for (int m = 0; m < 2; ++m)
#pragma unroll
      for (int n = 0; n < 8; ++n)
#pragma unroll
        for (int i = 0; i < 4; ++i) acc[m][n][i] = 0.0f;
    gemm_tile<2, 12, 8>(Xs, 392, wf + OF_UW1 + (size_t)(w * 8) * 12 * 512, acc, lane);
    __syncthreads();
#pragma unroll
    for (int n = 0; n < 8; ++n) {
      const int col = w * 128 + n * 16 + cw;
      const float bias = ub1[col];
#pragma unroll
      for (int m = 0; m < 2; ++m)
#pragma unroll
        for (int q = 0; q < 4; ++q) {
          const int row = m * 16 + rq + q;
          Xs[row * 392 + col] = f2bf(fmaxf(acc[m][n][q] + bias, 0.0f));
        }
    }
  }
  __syncthreads();

  // Layer 2: 256 -> 256, relu, in-place on Xs.
  {
    f32x4 acc[2][8];
#pragma unroll
    for (int m = 0; m < 2; ++m)
#pragma unroll
      for (int n = 0; n < 8; ++n)
#pragma unroll
        for (int i = 0; i < 4; ++i) acc[m][n][i] = 0.0f;
    gemm_tile<2, 8, 8>(Xs, 392, wf + OF_UW2 + (size_t)(w * 8) * 8 * 512, acc, lane);
    __syncthreads();
#pragma unroll
    for (int n = 0; n < 8; ++n) {
      const int col = w * 128 + n * 16 + cw;
      const float bias = ub2[col];
#pragma unroll
      for (int m = 0; m < 2; ++m)
#pragma unroll
        for (int q = 0; q < 4; ++q) {
          const int row = m * 16 + rq + q;
          Xs[row * 392 + col] = f2bf(fmaxf(acc[m][n][q] + bias, 0.0f));
        }
    }
  }
  __syncthreads();

  // Layer 3: 256 -> 128 -> out (fp32). Each wave: 64 output cols.
  {
    f32x4 acc[2][4];
#pragma unroll
    for (int m = 0; m < 2; ++m)
#pragma unroll
      for (int n = 0; n < 4; ++n)
#pragma unroll
        for (int i = 0; i < 4; ++i) acc[m][n][i] = 0.0f;
    gemm_tile<2, 8, 4>(Xs, 392, wf + OF_UW3 + (size_t)(w * 4) * 8 * 512, acc, lane);
#pragma unroll
    for (int n = 0; n < 4; ++n) {
      const int col = w * 64 + n * 16 + cw;
      const float bias = ub3[col];
#pragma unroll
      for (int m = 0; m < 2; ++m)
#pragma unroll
        for (int q = 0; q < 4; ++q) {
          const int row = m * 16 + rq + q;
          out[(size_t)(n0 + row) * 128 + col] = acc[m][n][q] + bias;
        }
    }
  }
}

extern "C" void kernel_launch(void* const* d_in, const int* in_sizes, int n_in,
                              void* d_out, int out_size, void* d_ws, size_t ws_size,
                              hipStream_t stream) {
  const float* ns   = (const float*)d_in[0];
  const float* edg  = (const float*)d_in[1];
  const int* verts  = (const int*)d_in[2];
  const float* mW1  = (const float*)d_in[3];
  const float* mb1  = (const float*)d_in[4];
  const float* mW2  = (const float*)d_in[5];
  const float* mb2  = (const float*)d_in[6];
  const float* mW3  = (const float*)d_in[7];
  const float* mb3  = (const float*)d_in[8];
  const float* uW1  = (const float*)d_in[9];
  const float* ub1  = (const float*)d_in[10];
  const float* uW2  = (const float*)d_in[11];
  const float* ub2  = (const float*)d_in[12];
  const float* uW3  = (const float*)d_in[13];
  const float* ub3  = (const float*)d_in[14];
  float* out = (float*)d_out;

  const int msg_lds = 64 * 328 * 2;  // 41984 B -> 3 blocks/CU
  const int upd_lds = 32 * 392 * 2;  // 25088 B -> 6 blocks/CU

  if (ws_size >= WS_NEED) {
    // CSR path: no fp32 scatter-atomics; bf16 node table for the gather.
    unsigned short* msgs = (unsigned short*)d_ws;
    unsigned short* nsb  = (unsigned short*)((char*)d_ws + WS_NSB_OFF);
    int* eidx = (int*)((char*)d_ws + WS_EIDX_OFF);
    int* cnt  = (int*)((char*)d_ws + WS_CNT_OFF);
    unsigned short* wf = (unsigned short*)((char*)d_ws + WS_WF_OFF);

    (void)hipMemsetAsync(cnt, 0, WS_CNT_BYTES, stream);
    prep_weights<<<736, 64, 0, stream>>>(mW1, mW2, mW3, uW1, uW2, uW3, wf);
    cvt_ns<<<NNODES * 128 / 8 / 256, 256, 0, stream>>>(ns, nsb);
    fill_csr<<<2 * NEDGES / 256, 256, 0, stream>>>(verts, cnt, eidx);
    msg_kernel<false><<<NEDGES / 64, 256, msg_lds, stream>>>(
        ns, nsb, edg, verts, wf, mb1, mb2, mb3, nullptr, msgs);
    upd_kernel<true><<<NNODES / 32, 128, upd_lds, stream>>>(
        ns, nullptr, msgs, cnt, eidx, wf, ub1, ub2, ub3, out);
  } else {
    // Fallback: atomic path.
    float* summed = (float*)d_ws;
    unsigned short* wf = (unsigned short*)((char*)d_ws + WS_SUMMED_BYTES);

    (void)hipMemsetAsync(summed, 0, WS_SUMMED_BYTES, stream);
    prep_weights<<<736, 64, 0, stream>>>(mW1, mW2, mW3, uW1, uW2, uW3, wf);
    msg_kernel<true><<<NEDGES / 64, 256, msg_lds, stream>>>(
        ns, nullptr, edg, verts, wf, mb1, mb2, mb3, summed, nullptr);
    upd_kernel<false><<<NNODES / 32, 128, upd_lds, stream>>>(
        ns, summed, nullptr, nullptr, nullptr, wf, ub1, ub2, ub3, out);
  }
}